// Round 1
// baseline (615.084 us; speedup 1.0000x reference)
//
#include <hip/hip_runtime.h>

// Problem constants (BH,L,D fixed by the reference)
#define BH 16
#define L 2048
#define D 64
#define QB 64        // q rows per block
#define KB 64        // keys per k-tile
#define STRIDE 72    // u16 stride for 64-wide bf16 LDS tiles: 144B = 16B-aligned, <=2-way banks
#define SCALE 0.125f // 1/temperature (8.0)
#define MASK_FILL -65504.0f

typedef __bf16 bf16x8 __attribute__((ext_vector_type(8)));
typedef float f32x4 __attribute__((ext_vector_type(4)));

__device__ __forceinline__ unsigned short f2bf(float f) {
    union { float f; unsigned u; } x; x.f = f;
    unsigned r = (x.u + 0x7FFFu + ((x.u >> 16) & 1u)) >> 16;  // RNE
    return (unsigned short)r;
}
__device__ __forceinline__ float bf2f(unsigned short h) {
    union { unsigned u; float f; } x; x.u = ((unsigned)h) << 16;
    return x.f;
}

extern "C" __global__ __launch_bounds__(256, 2)
void sdpa_kernel(const float* __restrict__ q, const float* __restrict__ k,
                 const float* __restrict__ v, const int* __restrict__ mask,
                 float* __restrict__ out, float* __restrict__ attn)
{
    __shared__ unsigned short sQ[QB * STRIDE];   // bf16 Q tile [qrow][d]
    __shared__ unsigned short sK[KB * STRIDE];   // bf16 K tile [key][d]
    __shared__ unsigned short sVt[D * STRIDE];   // bf16 V tile TRANSPOSED [d][key]
    __shared__ unsigned short sP[QB * STRIDE];   // bf16 P tile [qrow][key]
    __shared__ unsigned long long sM[QB * 33];   // mask bits: [row][it*4+j], stride 33 u64

    const int tid  = threadIdx.x;
    const int lane = tid & 63;
    const int w    = tid >> 6;          // wave id 0..3; wave handles q rows w*16..w*16+15
    const int quad = lane >> 4;
    const int l15  = lane & 15;

    const int p  = blockIdx.x;
    const int bh = p & (BH - 1);        // bh-minor: XCD x (p%8) sees only bh {x, x+8} -> K/V fit L2
    const int qb = p >> 4;
    const int q0 = qb * QB;

    const size_t base = (size_t)bh * L * D;
    const float* Qb = q + base + (size_t)q0 * D;
    const float* Kb = k + base;
    const float* Vb = v + base;
    const int*   Mb = mask + (size_t)bh * L * L + (size_t)q0 * L;
    float*       Ab = attn + (size_t)bh * L * L + (size_t)q0 * L;
    float*       Ob = out  + base + (size_t)q0 * D;

    // ---- stage Q tile (fp32 -> bf16) ----
    {
        const float2* Qs = (const float2*)Qb;
        for (int i = 0; i < 8; ++i) {
            int idx = i * 256 + tid;            // 0..2047 float2s, linear in memory
            int row = idx >> 5;
            int d2  = idx & 31;
            float2 val = Qs[idx];
            unsigned pk = (unsigned)f2bf(val.x) | ((unsigned)f2bf(val.y) << 16);
            *(unsigned*)&sQ[row * STRIDE + d2 * 2] = pk;
        }
    }

    // ---- stage mask bits: read int32 mask ONCE, ballot-compact to 1 bit/elem ----
    // word layout: sM[row*33 + (k>>8)*4 + (k&3)], bit index (k>>2)&63
    for (int rr = 0; rr < 16; ++rr) {
        int row = w * 16 + rr;
        const int4* Ms = (const int4*)(Mb + (size_t)row * L);
        for (int it = 0; it < 8; ++it) {
            int4 mv = Ms[it * 64 + lane];       // k = it*256 + lane*4 + j
            unsigned long long b0 = __ballot(mv.x != 0);
            unsigned long long b1 = __ballot(mv.y != 0);
            unsigned long long b2 = __ballot(mv.z != 0);
            unsigned long long b3 = __ballot(mv.w != 0);
            if (lane == 0) {
                unsigned long long* dst = &sM[row * 33 + it * 4];
                dst[0] = b0; dst[1] = b1; dst[2] = b2; dst[3] = b3;
            }
        }
    }
    __syncthreads();

    // ---- Q fragments (constant across all k-tiles) ----
    // A-frag layout: A[m=lane&15][k=quad*8+j]
    const int qrow = w * 16 + l15;
    bf16x8 qa0 = *(const bf16x8*)&sQ[qrow * STRIDE + quad * 8];
    bf16x8 qa1 = *(const bf16x8*)&sQ[qrow * STRIDE + quad * 8 + 32];

    // ================= PASS 1: row sums of exp(masked scaled scores) ==========
    float lsum[4] = {0.f, 0.f, 0.f, 0.f};
    for (int kt = 0; kt < L / KB; ++kt) {
        const int k0 = kt * KB;
        __syncthreads();
        {   // stage K tile
            const float2* Ks = (const float2*)(Kb + (size_t)k0 * D);
            for (int i = 0; i < 8; ++i) {
                int idx = i * 256 + tid;
                int row = idx >> 5;
                int d2  = idx & 31;
                float2 val = Ks[idx];
                unsigned pk = (unsigned)f2bf(val.x) | ((unsigned)f2bf(val.y) << 16);
                *(unsigned*)&sK[row * STRIDE + d2 * 2] = pk;
            }
        }
        __syncthreads();

        f32x4 acc[4];
        for (int nt = 0; nt < 4; ++nt) {
            bf16x8 b0 = *(const bf16x8*)&sK[(nt * 16 + l15) * STRIDE + quad * 8];
            bf16x8 b1 = *(const bf16x8*)&sK[(nt * 16 + l15) * STRIDE + quad * 8 + 32];
            f32x4 c = {0.f, 0.f, 0.f, 0.f};
            c = __builtin_amdgcn_mfma_f32_16x16x32_bf16(qa0, b0, c, 0, 0, 0);
            c = __builtin_amdgcn_mfma_f32_16x16x32_bf16(qa1, b1, c, 0, 0, 0);
            acc[nt] = c;
        }
        // C layout: row = quad*4+reg, col = lane&15; col k = k0 + nt*16 + l15
        const int widx  = (k0 >> 8) * 4 + (lane & 3);
        const int bsh0  = (k0 >> 2) + (l15 >> 2);
        for (int r = 0; r < 4; ++r) {
            int row = w * 16 + quad * 4 + r;
            unsigned long long mw = sM[row * 33 + widx];
            float s = 0.f;
            for (int nt = 0; nt < 4; ++nt) {
                float val = acc[nt][r] * SCALE;
                int bit = (int)((mw >> ((bsh0 + nt * 4) & 63)) & 1ull);
                val = bit ? MASK_FILL : val;      // exp(-65504) underflows to 0, like ref
                s += __expf(val);
            }
            lsum[r] += s;
        }
    }
    // reduce row sums across the 16 lanes that share a row
    for (int off = 1; off < 16; off <<= 1)
        for (int r = 0; r < 4; ++r)
            lsum[r] += __shfl_xor(lsum[r], off, 64);
    float rinv[4];
    for (int r = 0; r < 4; ++r) rinv[r] = 1.0f / lsum[r];

    // ================= PASS 2: P = exp(S)/l, write attn, O += P@V ============
    f32x4 oacc[4];
    for (int nt = 0; nt < 4; ++nt) oacc[nt] = (f32x4){0.f, 0.f, 0.f, 0.f};

    for (int kt = 0; kt < L / KB; ++kt) {
        const int k0 = kt * KB;
        __syncthreads();
        {   // stage K tile
            const float2* Ks = (const float2*)(Kb + (size_t)k0 * D);
            for (int i = 0; i < 8; ++i) {
                int idx = i * 256 + tid;
                int row = idx >> 5;
                int d2  = idx & 31;
                float2 val = Ks[idx];
                unsigned pk = (unsigned)f2bf(val.x) | ((unsigned)f2bf(val.y) << 16);
                *(unsigned*)&sK[row * STRIDE + d2 * 2] = pk;
            }
        }
        {   // stage V tile transposed: wave w loads keys k0+16w..+16, lane=d
            unsigned pk[8];
            for (int jj = 0; jj < 16; ++jj) {
                float val = Vb[(size_t)(k0 + w * 16 + jj) * D + lane];
                unsigned short b = f2bf(val);
                if (jj & 1) pk[jj >> 1] |= ((unsigned)b) << 16;
                else        pk[jj >> 1]  = b;
            }
            uint4* dst = (uint4*)&sVt[lane * STRIDE + w * 16];
            dst[0] = make_uint4(pk[0], pk[1], pk[2], pk[3]);
            dst[1] = make_uint4(pk[4], pk[5], pk[6], pk[7]);
        }
        __syncthreads();

        // recompute S tile
        f32x4 acc[4];
        for (int nt = 0; nt < 4; ++nt) {
            bf16x8 b0 = *(const bf16x8*)&sK[(nt * 16 + l15) * STRIDE + quad * 8];
            bf16x8 b1 = *(const bf16x8*)&sK[(nt * 16 + l15) * STRIDE + quad * 8 + 32];
            f32x4 c = {0.f, 0.f, 0.f, 0.f};
            c = __builtin_amdgcn_mfma_f32_16x16x32_bf16(qa0, b0, c, 0, 0, 0);
            c = __builtin_amdgcn_mfma_f32_16x16x32_bf16(qa1, b1, c, 0, 0, 0);
            acc[nt] = c;
        }
        const int widx = (k0 >> 8) * 4 + (lane & 3);
        const int bsh0 = (k0 >> 2) + (l15 >> 2);
        for (int r = 0; r < 4; ++r) {
            int row = w * 16 + quad * 4 + r;
            unsigned long long mw = sM[row * 33 + widx];
            for (int nt = 0; nt < 4; ++nt) {
                float val = acc[nt][r] * SCALE;
                int bit = (int)((mw >> ((bsh0 + nt * 4) & 63)) & 1ull);
                val = bit ? MASK_FILL : val;
                float pr = __expf(val) * rinv[r];
                sP[row * STRIDE + nt * 16 + l15] = f2bf(pr);
            }
        }
        // write attn tile (own wave's rows), coalesced float4 stores
        for (int it = 0; it < 4; ++it) {
            int row = w * 16 + it * 4 + quad;
            unsigned long long pv = *(const unsigned long long*)&sP[row * STRIDE + l15 * 4];
            float4 o;
            o.x = bf2f((unsigned short)(pv         & 0xFFFF));
            o.y = bf2f((unsigned short)((pv >> 16) & 0xFFFF));
            o.z = bf2f((unsigned short)((pv >> 32) & 0xFFFF));
            o.w = bf2f((unsigned short)((pv >> 48) & 0xFFFF));
            *(float4*)&Ab[(size_t)row * L + k0 + l15 * 4] = o;
        }
        // O += P @ V   (A = P rows, B = Vt rows)
        {
            bf16x8 pa0 = *(const bf16x8*)&sP[qrow * STRIDE + quad * 8];
            bf16x8 pa1 = *(const bf16x8*)&sP[qrow * STRIDE + quad * 8 + 32];
            for (int nt = 0; nt < 4; ++nt) {
                bf16x8 vb0 = *(const bf16x8*)&sVt[(nt * 16 + l15) * STRIDE + quad * 8];
                bf16x8 vb1 = *(const bf16x8*)&sVt[(nt * 16 + l15) * STRIDE + quad * 8 + 32];
                oacc[nt] = __builtin_amdgcn_mfma_f32_16x16x32_bf16(pa0, vb0, oacc[nt], 0, 0, 0);
                oacc[nt] = __builtin_amdgcn_mfma_f32_16x16x32_bf16(pa1, vb1, oacc[nt], 0, 0, 0);
            }
        }
    }

    // ---- write O ----
    for (int nt = 0; nt < 4; ++nt)
        for (int r = 0; r < 4; ++r)
            Ob[(size_t)(w * 16 + quad * 4 + r) * D + nt * 16 + l15] = oacc[nt][r];
}

extern "C" void kernel_launch(void* const* d_in, const int* in_sizes, int n_in,
                              void* d_out, int out_size, void* d_ws, size_t ws_size,
                              hipStream_t stream)
{
    const float* q    = (const float*)d_in[0];
    const float* k    = (const float*)d_in[1];
    const float* v    = (const float*)d_in[2];
    const int*   mask = (const int*)d_in[3];
    float* out  = (float*)d_out;
    float* attn = out + (size_t)BH * L * D;   // outputs concatenated: [out | attn]

    dim3 grid(BH * (L / QB));   // 512 blocks
    dim3 block(256);
    hipLaunchKernelGGL(sdpa_kernel, grid, block, 0, stream,
                       q, k, v, mask, out, attn);
}

// Round 2
// 601.939 us; speedup vs baseline: 1.0218x; 1.0218x over previous
//
#include <hip/hip_runtime.h>

#define BH 16
#define L 2048
#define D 64
#define QB 32
#define KB 64
#define NKT (L / KB)
#define SCALE 0.125f
#define MASK_FILL -65504.0f

typedef __bf16 bf16x8 __attribute__((ext_vector_type(8)));
typedef float f32x4 __attribute__((ext_vector_type(4)));

__device__ __forceinline__ unsigned f2bf(float f) {
    union { float f; unsigned u; } x; x.f = f;
    return (x.u + 0x7FFFu + ((x.u >> 16) & 1u)) >> 16;   // RNE
}
__device__ __forceinline__ float bf2f(unsigned short h) {
    union { unsigned u; float f; } x; x.u = ((unsigned)h) << 16;
    return x.f;
}

// async global->LDS, 16B per lane. LDS dst is wave-uniform base + lane*16.
__device__ __forceinline__ void gload16(const void* g, void* l) {
    __builtin_amdgcn_global_load_lds(
        (const __attribute__((address_space(1))) unsigned int*)g,
        (__attribute__((address_space(3))) unsigned int*)l, 16, 0, 0);
}

// ============================ pre-pass kernels =============================

// K fp32 -> bf16, chunk-swizzled: ws_K chunk index (bh*L+key)*8 + (c ^ (key&7))
extern "C" __global__ __launch_bounds__(256)
void preK(const float* __restrict__ k, uint4* __restrict__ wsK)
{
    int idx = blockIdx.x * 256 + threadIdx.x;      // 0..262143 chunks
    int c   = idx & 7;
    int key = (idx >> 3) & (L - 1);
    int bh  = idx >> 14;
    const float4* src = (const float4*)(k + ((size_t)(bh * L + key) * D + c * 8));
    float4 a = src[0], b = src[1];
    uint4 o;
    o.x = f2bf(a.x) | (f2bf(a.y) << 16);
    o.y = f2bf(a.z) | (f2bf(a.w) << 16);
    o.z = f2bf(b.x) | (f2bf(b.y) << 16);
    o.w = f2bf(b.z) | (f2bf(b.w) << 16);
    wsK[(size_t)(bh * L + key) * 8 + (c ^ (key & 7))] = o;
}

// V fp32 [key][d] -> bf16 transposed+tiled ws_Vt[bh][kt][d][key64], swizzle c^(d&7)
extern "C" __global__ __launch_bounds__(256)
void preV(const float* __restrict__ v, uint4* __restrict__ wsVt)
{
    __shared__ float sT[64 * 68];
    int b = blockIdx.x;            // 16*32 tiles
    int bh = b >> 5, kt = b & 31;
    const float4* src = (const float4*)(v + ((size_t)bh * L + kt * 64) * D);
    int t = threadIdx.x;
    #pragma unroll
    for (int i = 0; i < 4; ++i) {
        int i4 = i * 256 + t;               // 1024 float4s = 64x64 tile
        int key = i4 >> 4, c4 = i4 & 15;
        float4 val = src[i4];
        *(float4*)&sT[key * 68 + c4 * 4] = val;
    }
    __syncthreads();
    int d = t >> 2, cg = t & 3;
    #pragma unroll
    for (int j = 0; j < 2; ++j) {
        int c = cg + j * 4;                 // key-chunk 0..7
        unsigned pk[4];
        #pragma unroll
        for (int e = 0; e < 4; ++e) {
            float x0 = sT[(c * 8 + e * 2    ) * 68 + d];
            float x1 = sT[(c * 8 + e * 2 + 1) * 68 + d];
            pk[e] = f2bf(x0) | (f2bf(x1) << 16);
        }
        wsVt[((size_t)(bh * 32 + kt) * 64 + d) * 8 + (c ^ (d & 7))] =
            make_uint4(pk[0], pk[1], pk[2], pk[3]);
    }
}

// mask int32 -> bitmask: ws_M[bh*L+row][wd] u64, bit j = col wd*64+j
extern "C" __global__ __launch_bounds__(256)
void preM(const int* __restrict__ mask, unsigned long long* __restrict__ wsM)
{
    __shared__ unsigned long long sW[16 * 32];
    int b = blockIdx.x;                     // 2048 blocks, 16 rows each
    size_t row0 = (size_t)b * 16;
    int w = threadIdx.x >> 6, lane = threadIdx.x & 63;
    const int* src = mask + row0 * L;
    for (int rr = 0; rr < 4; ++rr) {
        int r = w * 4 + rr;
        #pragma unroll 8
        for (int wd = 0; wd < 32; ++wd) {
            int val = src[(size_t)r * L + wd * 64 + lane];
            unsigned long long bal = __ballot(val != 0);
            if (lane == 0) sW[r * 32 + wd] = bal;
        }
    }
    __syncthreads();
    int t = threadIdx.x;
    ((uint4*)wsM)[(size_t)b * 256 + t] = ((const uint4*)sW)[t];
}

// ============================== main kernel ================================

extern "C" __global__ __launch_bounds__(256, 4)
void sdpa_main(const float* __restrict__ q, const uint4* __restrict__ gKall,
               const uint4* __restrict__ gVall, const unsigned long long* __restrict__ wsM,
               float* __restrict__ out, float* __restrict__ attn)
{
    __shared__ unsigned short sK[2][KB * 64];    // bf16, chunk-swizzled, unpadded
    __shared__ unsigned short sVt[2][D * 64];
    __shared__ unsigned short sP[QB * 72];       // padded stride for A-frag reads
    __shared__ float sPart[4][16];

    const int tid = threadIdx.x, lane = tid & 63, w = tid >> 6;
    const int wr = w & 1, wn = w >> 1;           // row-tile / nt-pair split
    const int quad = lane >> 4, l15 = lane & 15;
    const int p = blockIdx.x, bh = p & 15, qb = p >> 4, q0 = qb * QB;

    const uint4* gK = gKall + (size_t)bh * L * 8;
    const uint4* gV = gVall + (size_t)bh * L * 8;

    // ---- Q fragments straight from global (once) ----
    const float* Qp = q + (size_t)(bh * L + q0 + wr * 16 + l15) * D + quad * 8;
    float4 qv0 = *(const float4*)(Qp);
    float4 qv1 = *(const float4*)(Qp + 4);
    float4 qv2 = *(const float4*)(Qp + 32);
    float4 qv3 = *(const float4*)(Qp + 36);
    union { bf16x8 v; unsigned short s[8]; } qa0u, qa1u;
    qa0u.s[0] = f2bf(qv0.x); qa0u.s[1] = f2bf(qv0.y); qa0u.s[2] = f2bf(qv0.z); qa0u.s[3] = f2bf(qv0.w);
    qa0u.s[4] = f2bf(qv1.x); qa0u.s[5] = f2bf(qv1.y); qa0u.s[6] = f2bf(qv1.z); qa0u.s[7] = f2bf(qv1.w);
    qa1u.s[0] = f2bf(qv2.x); qa1u.s[1] = f2bf(qv2.y); qa1u.s[2] = f2bf(qv2.z); qa1u.s[3] = f2bf(qv2.w);
    qa1u.s[4] = f2bf(qv3.x); qa1u.s[5] = f2bf(qv3.y); qa1u.s[6] = f2bf(qv3.z); qa1u.s[7] = f2bf(qv3.w);
    const bf16x8 qa0 = qa0u.v, qa1 = qa1u.v;

    const unsigned long long* Mw = wsM + (size_t)(bh * L + q0 + wr * 16 + quad * 4) * 32;

    auto stageK = [&](int kt, int buf) {
        const uint4* s = gK + (size_t)kt * 512 + w * 128 + lane;
        gload16(s,      &sK[buf][(w * 128) * 8]);
        gload16(s + 64, &sK[buf][(w * 128 + 64) * 8]);
    };
    auto stageV = [&](int kt, int buf) {
        const uint4* s = gV + (size_t)kt * 512 + w * 128 + lane;
        gload16(s,      &sVt[buf][(w * 128) * 8]);
        gload16(s + 64, &sVt[buf][(w * 128 + 64) * 8]);
    };
    auto scompute = [&](int cur, f32x4* acc) {
        #pragma unroll
        for (int j = 0; j < 2; ++j) {
            int key = (wn * 2 + j) * 16 + l15;
            const bf16x8 b0 = *(const bf16x8*)&sK[cur][key * 64 + ((quad     ^ (key & 7)) * 8)];
            const bf16x8 b1 = *(const bf16x8*)&sK[cur][key * 64 + (((quad+4) ^ (key & 7)) * 8)];
            f32x4 c = {0.f, 0.f, 0.f, 0.f};
            c = __builtin_amdgcn_mfma_f32_16x16x32_bf16(qa0, b0, c, 0, 0, 0);
            c = __builtin_amdgcn_mfma_f32_16x16x32_bf16(qa1, b1, c, 0, 0, 0);
            acc[j] = c;
        }
    };

    // ===================== PASS 1: row sums of exp =====================
    float lsum[4] = {0.f, 0.f, 0.f, 0.f};
    stageK(0, 0);
    __syncthreads();
    for (int kt = 0; kt < NKT; ++kt) {
        int cur = kt & 1;
        if (kt + 1 < NKT) stageK(kt + 1, cur ^ 1);   // async prefetch
        unsigned long long mw[4];
        #pragma unroll
        for (int r = 0; r < 4; ++r) mw[r] = Mw[r * 32 + kt];
        f32x4 acc[2];
        scompute(cur, acc);
        #pragma unroll
        for (int j = 0; j < 2; ++j) {
            int sh = (wn * 2 + j) * 16 + l15;
            #pragma unroll
            for (int r = 0; r < 4; ++r) {
                float val = acc[j][r] * SCALE;
                val = ((mw[r] >> sh) & 1ull) ? MASK_FILL : val;
                lsum[r] += __expf(val);
            }
        }
        __syncthreads();   // drains prefetch (overlapped with compute above)
    }
    #pragma unroll
    for (int off = 1; off < 16; off <<= 1)
        #pragma unroll
        for (int r = 0; r < 4; ++r) lsum[r] += __shfl_xor(lsum[r], off, 64);
    if (l15 == 0) {
        #pragma unroll
        for (int r = 0; r < 4; ++r) sPart[w][quad * 4 + r] = lsum[r];
    }
    __syncthreads();
    float rinv[4];
    #pragma unroll
    for (int r = 0; r < 4; ++r)
        rinv[r] = 1.0f / (sPart[wr][quad * 4 + r] + sPart[wr + 2][quad * 4 + r]);

    // ===================== PASS 2: attn + O = P@V =====================
    f32x4 oacc[2];
    oacc[0] = (f32x4){0.f, 0.f, 0.f, 0.f};
    oacc[1] = (f32x4){0.f, 0.f, 0.f, 0.f};
    float* Ab = attn + ((size_t)bh * L + q0) * L;

    stageK(0, 0); stageV(0, 0);
    __syncthreads();
    for (int kt = 0; kt < NKT; ++kt) {
        int cur = kt & 1;
        if (kt + 1 < NKT) { stageK(kt + 1, cur ^ 1); stageV(kt + 1, cur ^ 1); }
        unsigned long long mw[4];
        #pragma unroll
        for (int r = 0; r < 4; ++r) mw[r] = Mw[r * 32 + kt];
        f32x4 acc[2];
        scompute(cur, acc);
        #pragma unroll
        for (int j = 0; j < 2; ++j) {
            int col = (wn * 2 + j) * 16 + l15;
            #pragma unroll
            for (int r = 0; r < 4; ++r) {
                float val = acc[j][r] * SCALE;
                val = ((mw[r] >> col) & 1ull) ? MASK_FILL : val;
                float pr = __expf(val) * rinv[r];
                int row = wr * 16 + quad * 4 + r;
                Ab[(size_t)row * L + kt * 64 + col] = pr;          // fp32 attn
                sP[row * 72 + col] = (unsigned short)f2bf(pr);     // bf16 for PV
            }
        }
        __syncthreads();   // barrier A: sP visible, prefetch drained
        {
            const bf16x8 pa0 = *(const bf16x8*)&sP[(wr * 16 + l15) * 72 + quad * 8];
            const bf16x8 pa1 = *(const bf16x8*)&sP[(wr * 16 + l15) * 72 + quad * 8 + 32];
            #pragma unroll
            for (int j = 0; j < 2; ++j) {
                int dd = (wn * 2 + j) * 16 + l15;
                const bf16x8 vb0 = *(const bf16x8*)&sVt[cur][dd * 64 + ((quad     ^ (dd & 7)) * 8)];
                const bf16x8 vb1 = *(const bf16x8*)&sVt[cur][dd * 64 + (((quad+4) ^ (dd & 7)) * 8)];
                oacc[j] = __builtin_amdgcn_mfma_f32_16x16x32_bf16(pa0, vb0, oacc[j], 0, 0, 0);
                oacc[j] = __builtin_amdgcn_mfma_f32_16x16x32_bf16(pa1, vb1, oacc[j], 0, 0, 0);
            }
        }
        __syncthreads();   // barrier B: buffers free for next prefetch
    }

    float* Ob = out + ((size_t)bh * L + q0) * D;
    #pragma unroll
    for (int j = 0; j < 2; ++j)
        #pragma unroll
        for (int r = 0; r < 4; ++r)
            Ob[(size_t)(wr * 16 + quad * 4 + r) * D + (wn * 2 + j) * 16 + l15] = oacc[j][r];
}

// ===================== fallback (round-1 kernel, known good) ==============

extern "C" __global__ __launch_bounds__(256, 2)
void sdpa_kernel(const float* __restrict__ q, const float* __restrict__ k,
                 const float* __restrict__ v, const int* __restrict__ mask,
                 float* __restrict__ out, float* __restrict__ attn)
{
    __shared__ unsigned short fQ[64 * 72];
    __shared__ unsigned short fK[64 * 72];
    __shared__ unsigned short fVt[64 * 72];
    __shared__ unsigned short fP[64 * 72];
    __shared__ unsigned long long fM[64 * 33];

    const int tid  = threadIdx.x;
    const int lane = tid & 63;
    const int w    = tid >> 6;
    const int quad = lane >> 4;
    const int l15  = lane & 15;

    const int p  = blockIdx.x;
    const int bh = p & (BH - 1);
    const int qb = p >> 4;
    const int q0 = qb * 64;

    const size_t base = (size_t)bh * L * D;
    const float* Qb = q + base + (size_t)q0 * D;
    const float* Kb = k + base;
    const float* Vb = v + base;
    const int*   Mb = mask + (size_t)bh * L * L + (size_t)q0 * L;
    float*       Ab = attn + (size_t)bh * L * L + (size_t)q0 * L;
    float*       Ob = out  + base + (size_t)q0 * D;

    {
        const float2* Qs = (const float2*)Qb;
        for (int i = 0; i < 8; ++i) {
            int idx = i * 256 + tid;
            int row = idx >> 5, d2 = idx & 31;
            float2 val = Qs[idx];
            unsigned pk = f2bf(val.x) | (f2bf(val.y) << 16);
            *(unsigned*)&fQ[row * 72 + d2 * 2] = pk;
        }
    }
    for (int rr = 0; rr < 16; ++rr) {
        int row = w * 16 + rr;
        const int4* Ms = (const int4*)(Mb + (size_t)row * L);
        for (int it = 0; it < 8; ++it) {
            int4 mv = Ms[it * 64 + lane];
            unsigned long long b0 = __ballot(mv.x != 0);
            unsigned long long b1 = __ballot(mv.y != 0);
            unsigned long long b2 = __ballot(mv.z != 0);
            unsigned long long b3 = __ballot(mv.w != 0);
            if (lane == 0) {
                unsigned long long* dst = &fM[row * 33 + it * 4];
                dst[0] = b0; dst[1] = b1; dst[2] = b2; dst[3] = b3;
            }
        }
    }
    __syncthreads();

    const int qrow = w * 16 + l15;
    bf16x8 qa0 = *(const bf16x8*)&fQ[qrow * 72 + quad * 8];
    bf16x8 qa1 = *(const bf16x8*)&fQ[qrow * 72 + quad * 8 + 32];

    float lsum[4] = {0.f, 0.f, 0.f, 0.f};
    for (int kt = 0; kt < 32; ++kt) {
        const int k0 = kt * 64;
        __syncthreads();
        {
            const float2* Ks = (const float2*)(Kb + (size_t)k0 * D);
            for (int i = 0; i < 8; ++i) {
                int idx = i * 256 + tid;
                int row = idx >> 5, d2 = idx & 31;
                float2 val = Ks[idx];
                unsigned pk = f2bf(val.x) | (f2bf(val.y) << 16);
                *(unsigned*)&fK[row * 72 + d2 * 2] = pk;
            }
        }
        __syncthreads();
        f32x4 acc[4];
        for (int nt = 0; nt < 4; ++nt) {
            bf16x8 b0 = *(const bf16x8*)&fK[(nt * 16 + l15) * 72 + quad * 8];
            bf16x8 b1 = *(const bf16x8*)&fK[(nt * 16 + l15) * 72 + quad * 8 + 32];
            f32x4 c = {0.f, 0.f, 0.f, 0.f};
            c = __builtin_amdgcn_mfma_f32_16x16x32_bf16(qa0, b0, c, 0, 0, 0);
            c = __builtin_amdgcn_mfma_f32_16x16x32_bf16(qa1, b1, c, 0, 0, 0);
            acc[nt] = c;
        }
        const int widx = (k0 >> 8) * 4 + (lane & 3);
        const int bsh0 = (k0 >> 2) + (l15 >> 2);
        for (int r = 0; r < 4; ++r) {
            int row = w * 16 + quad * 4 + r;
            unsigned long long mwv = fM[row * 33 + widx];
            float s = 0.f;
            for (int nt = 0; nt < 4; ++nt) {
                float val = acc[nt][r] * SCALE;
                int bit = (int)((mwv >> ((bsh0 + nt * 4) & 63)) & 1ull);
                val = bit ? MASK_FILL : val;
                s += __expf(val);
            }
            lsum[r] += s;
        }
    }
    for (int off = 1; off < 16; off <<= 1)
        for (int r = 0; r < 4; ++r) lsum[r] += __shfl_xor(lsum[r], off, 64);
    float rinv[4];
    for (int r = 0; r < 4; ++r) rinv[r] = 1.0f / lsum[r];

    f32x4 oacc[4];
    for (int nt = 0; nt < 4; ++nt) oacc[nt] = (f32x4){0.f, 0.f, 0.f, 0.f};

    for (int kt = 0; kt < 32; ++kt) {
        const int k0 = kt * 64;
        __syncthreads();
        {
            const float2* Ks = (const float2*)(Kb + (size_t)k0 * D);
            for (int i = 0; i < 8; ++i) {
                int idx = i * 256 + tid;
                int row = idx >> 5, d2 = idx & 31;
                float2 val = Ks[idx];
                unsigned pk = f2bf(val.x) | (f2bf(val.y) << 16);
                *(unsigned*)&fK[row * 72 + d2 * 2] = pk;
            }
        }
        {
            unsigned pk[8];
            for (int jj = 0; jj < 16; ++jj) {
                float val = Vb[(size_t)(k0 + w * 16 + jj) * D + lane];
                unsigned bv = f2bf(val);
                if (jj & 1) pk[jj >> 1] |= bv << 16;
                else        pk[jj >> 1]  = bv;
            }
            uint4* dst = (uint4*)&fVt[lane * 72 + w * 16];
            dst[0] = make_uint4(pk[0], pk[1], pk[2], pk[3]);
            dst[1] = make_uint4(pk[4], pk[5], pk[6], pk[7]);
        }
        __syncthreads();
        f32x4 acc[4];
        for (int nt = 0; nt < 4; ++nt) {
            bf16x8 b0 = *(const bf16x8*)&fK[(nt * 16 + l15) * 72 + quad * 8];
            bf16x8 b1 = *(const bf16x8*)&fK[(nt * 16 + l15) * 72 + quad * 8 + 32];
            f32x4 c = {0.f, 0.f, 0.f, 0.f};
            c = __builtin_amdgcn_mfma_f32_16x16x32_bf16(qa0, b0, c, 0, 0, 0);
            c = __builtin_amdgcn_mfma_f32_16x16x32_bf16(qa1, b1, c, 0, 0, 0);
            acc[nt] = c;
        }
        const int widx = (k0 >> 8) * 4 + (lane & 3);
        const int bsh0 = (k0 >> 2) + (l15 >> 2);
        for (int r = 0; r < 4; ++r) {
            int row = w * 16 + quad * 4 + r;
            unsigned long long mwv = fM[row * 33 + widx];
            for (int nt = 0; nt < 4; ++nt) {
                float val = acc[nt][r] * SCALE;
                int bit = (int)((mwv >> ((bsh0 + nt * 4) & 63)) & 1ull);
                val = bit ? MASK_FILL : val;
                float pr = __expf(val) * rinv[r];
                fP[row * 72 + nt * 16 + l15] = (unsigned short)f2bf(pr);
            }
        }
        for (int it = 0; it < 4; ++it) {
            int row = w * 16 + it * 4 + quad;
            unsigned long long pv = *(const unsigned long long*)&fP[row * 72 + l15 * 4];
            float4 o;
            o.x = bf2f((unsigned short)(pv         & 0xFFFF));
            o.y = bf2f((unsigned short)((pv >> 16) & 0xFFFF));
            o.z = bf2f((unsigned short)((pv >> 32) & 0xFFFF));
            o.w = bf2f((unsigned short)((pv >> 48) & 0xFFFF));
            *(float4*)&Ab[(size_t)row * L + k0 + l15 * 4] = o;
        }
        {
            bf16x8 pa0 = *(const bf16x8*)&fP[qrow * 72 + quad * 8];
            bf16x8 pa1 = *(const bf16x8*)&fP[qrow * 72 + quad * 8 + 32];
            for (int nt = 0; nt < 4; ++nt) {
                bf16x8 vb0 = *(const bf16x8*)&fVt[(nt * 16 + l15) * 72 + quad * 8];
                bf16x8 vb1 = *(const bf16x8*)&fVt[(nt * 16 + l15) * 72 + quad * 8 + 32];
                oacc[nt] = __builtin_amdgcn_mfma_f32_16x16x32_bf16(pa0, vb0, oacc[nt], 0, 0, 0);
                oacc[nt] = __builtin_amdgcn_mfma_f32_16x16x32_bf16(pa1, vb1, oacc[nt], 0, 0, 0);
            }
        }
    }
    for (int nt = 0; nt < 4; ++nt)
        for (int r = 0; r < 4; ++r)
            Ob[(size_t)(w * 16 + quad * 4 + r) * D + nt * 16 + l15] = oacc[nt][r];
}

// ============================== launch ====================================

extern "C" void kernel_launch(void* const* d_in, const int* in_sizes, int n_in,
                              void* d_out, int out_size, void* d_ws, size_t ws_size,
                              hipStream_t stream)
{
    const float* q    = (const float*)d_in[0];
    const float* k    = (const float*)d_in[1];
    const float* v    = (const float*)d_in[2];
    const int*   mask = (const int*)d_in[3];
    float* out  = (float*)d_out;
    float* attn = out + (size_t)BH * L * D;

    const size_t WS_K  = 0;
    const size_t WS_VT = (size_t)BH * L * D * 2;            // 4 MB
    const size_t WS_M  = WS_VT + (size_t)BH * L * D * 2;    // 8 MB
    const size_t NEED  = WS_M + (size_t)BH * L * 32 * 8;    // 16 MB

    if (ws_size >= NEED) {
        uint4* wsK  = (uint4*)((char*)d_ws + WS_K);
        uint4* wsVt = (uint4*)((char*)d_ws + WS_VT);
        unsigned long long* wsM = (unsigned long long*)((char*)d_ws + WS_M);
        hipLaunchKernelGGL(preK, dim3(1024), dim3(256), 0, stream, k, wsK);
        hipLaunchKernelGGL(preV, dim3(512),  dim3(256), 0, stream, v, wsVt);
        hipLaunchKernelGGL(preM, dim3(2048), dim3(256), 0, stream, mask, wsM);
        hipLaunchKernelGGL(sdpa_main, dim3(BH * (L / QB)), dim3(256), 0, stream,
                           q, (const uint4*)wsK, (const uint4*)wsVt, wsM, out, attn);
    } else {
        hipLaunchKernelGGL(sdpa_kernel, dim3(BH * (L / 64)), dim3(256), 0, stream,
                           q, k, v, mask, out, attn);
    }
}